// Round 8
// baseline (1077.098 us; speedup 1.0000x reference)
//
#include <hip/hip_runtime.h>
#include <cmath>

typedef float f32x4 __attribute__((ext_vector_type(4)));
typedef short short8 __attribute__((ext_vector_type(8)));

#define N_POINTS 524288
#define TMASK 0x7FFFFu   // T_MAX-1, hashed levels all have size 2^19
#define NCELLS 32768     // 32^3 Morton cells

struct HashCfg { int res[16]; int off[16]; unsigned hashed_mask; int total; };

// ---- ws layout (bytes) ----
#define S0_OFF   0
#define S1_OFF   1024
#define S2_OFF   2048
#define W2L_OFF  3328
#define B0_OFF   4608
#define B1_OFF   (B0_OFF + 49152)
#define B2_OFF   (B1_OFF + 131072)
#define TBF_OFF  (B2_OFF + 131072)   // bf16x2 table copy (~24.5 MB); sort arrays after

__device__ inline unsigned short f2bf(float f){
  unsigned u = __float_as_uint(f);
  u = (u + 0x7FFFu + ((u >> 16) & 1u)) >> 16;
  return (unsigned short)u;
}
__device__ inline float bf2f(unsigned short h){
  return __uint_as_float(((unsigned)h) << 16);
}
__device__ inline float softplus100_fast(float x){
  float y = 100.f * x;
  return 0.01f * (fmaxf(y, 0.f) + __logf(1.f + __expf(-fabsf(y))));
}
__device__ inline unsigned morton5(unsigned cx, unsigned cy, unsigned cz){
  unsigned k = 0;
  #pragma unroll
  for (int b = 0; b < 5; b++){
    k |= ((cx >> b) & 1u) << (3*b)
       | ((cy >> b) & 1u) << (3*b + 1)
       | ((cz >> b) & 1u) << (3*b + 2);
  }
  return k;
}

// ---- precompute 1: weight-norm row scales ----
__global__ void scale_kernel(const float* __restrict__ v0, const float* __restrict__ g0,
                             const float* __restrict__ v1, const float* __restrict__ g1,
                             const float* __restrict__ v2, const float* __restrict__ g2,
                             char* __restrict__ ws){
  int r = blockIdx.x * 256 + threadIdx.x;
  if (r < 256){
    float s = 0.f;
    for (int k = 0; k < 71; k++){ float t = v0[r*71+k]; s += t*t; }
    ((float*)(ws + S0_OFF))[r] = g0[r] / sqrtf(s);
  } else if (r < 512){
    int o = r - 256; float s = 0.f;
    for (int k = 0; k < 256; k++){ float t = v1[o*256+k]; s += t*t; }
    ((float*)(ws + S1_OFF))[o] = g1[o] / sqrtf(s);
  } else if (r < 769){
    int o = r - 512; float s = 0.f;
    for (int k = 0; k < 256; k++){ float t = v2[o*256+k]; s += t*t; }
    ((float*)(ws + S2_OFF))[o] = g2[o] / sqrtf(s);
  }
}

// ---- precompute 2: pack normalized weights into MFMA B-fragment order (bf16) ----
__global__ void pack_kernel(const float* __restrict__ v0, const float* __restrict__ v1,
                            const float* __restrict__ v2, char* __restrict__ ws){
  int i = blockIdx.x * 256 + threadIdx.x;
  const float* s0 = (const float*)(ws + S0_OFF);
  const float* s1 = (const float*)(ws + S1_OFF);
  const float* s2 = (const float*)(ws + S2_OFF);
  if (i < 24576){
    int j = i & 7, l = (i >> 3) & 63, q = i >> 9;
    int kt = q % 3, nt = q / 3;
    int k = kt*32 + (l >> 4)*8 + j, col = nt*16 + (l & 15);
    float v = (k < 71) ? v0[col*71 + k] * s0[col] : 0.f;
    ((unsigned short*)(ws + B0_OFF))[i] = f2bf(v);
  } else if (i < 90112){
    int e = i - 24576;
    int j = e & 7, l = (e >> 3) & 63, q = e >> 9;
    int kt = q & 7, nt = q >> 3;
    int k = kt*32 + (l >> 4)*8 + j, col = nt*16 + (l & 15);
    ((unsigned short*)(ws + B1_OFF))[e] = f2bf(v1[col*256 + k] * s1[col]);
  } else if (i < 155648){
    int e = i - 90112;
    int j = e & 7, l = (e >> 3) & 63, q = e >> 9;
    int kt = q & 7, nt = q >> 3;
    int k = kt*32 + (l >> 4)*8 + j, col = nt*16 + (l & 15);
    ((unsigned short*)(ws + B2_OFF))[e] = f2bf(v2[col*256 + k] * s2[col]);
  } else if (i < 155904){
    int k = i - 155648;
    ((float*)(ws + W2L_OFF))[k] = v2[256*256 + k] * s2[256];
  }
}

// ---- precompute 3: table f32 -> packed bf16x2 ----
__global__ void tconv_kernel(const float* __restrict__ table, char* __restrict__ ws, int total){
  int i = blockIdx.x * 256 + threadIdx.x;
  if (i < total){
    float2 v = ((const float2*)table)[i];
    ((unsigned*)(ws + TBF_OFF))[i] = ((unsigned)f2bf(v.x)) | (((unsigned)f2bf(v.y)) << 16);
  }
}

// ---- sort passes ----
__global__ void hist_kernel(const float* __restrict__ xin,
                            unsigned* __restrict__ hist, unsigned* __restrict__ keys){
  int i = blockIdx.x * 256 + threadIdx.x;
  float x0 = xin[i*3], x1 = xin[i*3+1], x2 = xin[i*3+2];
  unsigned cx = min(31u, (unsigned)(x0 * 32.f));
  unsigned cy = min(31u, (unsigned)(x1 * 32.f));
  unsigned cz = min(31u, (unsigned)(x2 * 32.f));
  unsigned k = morton5(cx, cy, cz);
  keys[i] = k;
  atomicAdd(&hist[k], 1u);
}

__global__ __launch_bounds__(1024) void scan_kernel(unsigned* __restrict__ hist){
  __shared__ unsigned sdata[1024];
  int t = threadIdx.x;
  unsigned loc[32];
  unsigned s = 0;
  #pragma unroll
  for (int k = 0; k < 32; k++){ loc[k] = hist[t*32 + k]; s += loc[k]; }
  sdata[t] = s;
  __syncthreads();
  for (int d = 1; d < 1024; d <<= 1){
    unsigned v = (t >= d) ? sdata[t - d] : 0u;
    __syncthreads();
    sdata[t] += v;
    __syncthreads();
  }
  unsigned run = (t == 0) ? 0u : sdata[t - 1];
  #pragma unroll
  for (int k = 0; k < 32; k++){ unsigned c = loc[k]; hist[t*32 + k] = run; run += c; }
}

// scatter + build pre-permuted coordinate array sx[r*3..] = x[perm[r]*3..]
__global__ void scatter_kernel(const float* __restrict__ xin,
                               const unsigned* __restrict__ keys,
                               unsigned* __restrict__ hist, int* __restrict__ perm,
                               float* __restrict__ sx){
  int i = blockIdx.x * 256 + threadIdx.x;
  unsigned k = keys[i];
  unsigned r = atomicAdd(&hist[k], 1u);
  perm[r] = i;
  sx[r*3]   = xin[i*3];
  sx[r*3+1] = xin[i*3+1];
  sx[r*3+2] = xin[i*3+2];
}

// ============================================================================
// Fused v6: 2 tiles of 64 sorted points per block. BOTH tiles' gathers are
// issued at block start (≈64 loads in flight/wave), so tile1's latency hides
// under tile0's entire MLP. Named vb0/vb1 arrays, static indexing only.
// ============================================================================
template<int USEBF>
__global__ __launch_bounds__(256) void fused6(
    const float* __restrict__ xin, const float* __restrict__ table,
    char* __restrict__ ws, const int* __restrict__ perm, const float* __restrict__ sx,
    const float* __restrict__ b0, const float* __restrict__ b1, const float* __restrict__ b2,
    float* __restrict__ out, HashCfg cfg)
{
  __shared__ unsigned short buf[64 * 256];  // swizzled: elem(row,col) at col^((row&7)<<3)
  __shared__ float colsc[4][64];
  __shared__ int pids_sh[2][64];

  const int tid = threadIdx.x;
  const int p   = tid & 63;
  const int grp = tid >> 6;
  const int l   = tid & 63;
  const int lr  = l & 15;
  const int lh  = l >> 4;
  const int wv  = grp;
  // bijective XCD swizzle over 4096 blocks (8 * 512)
  const int lb  = (blockIdx.x & 7) * 512 + (blockIdx.x >> 3);
  const int base_idx = lb * 128;

  const unsigned* __restrict__ tbf = (const unsigned*)(ws + TBF_OFF);
  const short8* B0p = (const short8*)(ws + B0_OFF);
  const short8* B1p = (const short8*)(ws + B1_OFF);
  const short8* B2p = (const short8*)(ws + B2_OFF);
  const float* w2l = (const float*)(ws + W2L_OFF);

  auto stB = [&](int row, int col, float v){
    buf[row*256 + (col ^ ((row & 7) << 3))] = f2bf(v);
  };
  auto ldB = [&](int row, int kb) -> short8 {
    return *(const short8*)&buf[row*256 + (kb ^ ((row & 7) << 3))];
  };

  if (tid < 128)
    pids_sh[tid >> 6][tid & 63] = perm ? perm[base_idx + tid] : (base_idx + tid);

  // coordinates for both tiles
  float a0, a1, a2, c0, c1, c2;
  {
    int i0 = base_idx + p, i1 = base_idx + 64 + p;
    const float* src = sx ? sx : xin;
    a0 = src[i0*3]; a1 = src[i0*3+1]; a2 = src[i0*3+2];
    c0 = src[i1*3]; c1 = src[i1*3+1]; c2 = src[i1*3+2];
  }

  unsigned vb0[4][8], vb1[4][8];
  float2   vf0[4][8], vf1[4][8];   // f32-table fallback only (dead when USEBF=1)

  auto issue = [&](float X, float Y, float Z, unsigned (&vb)[4][8], float2 (&vf)[4][8]){
    #pragma unroll
    for (int ii = 0; ii < 4; ii++){
      int lev = grp*4 + ii;
      int res = cfg.res[lev];
      float scl = (float)(res - 1);
      unsigned cx0 = (unsigned)floorf(X*scl);
      unsigned cy0 = (unsigned)floorf(Y*scl);
      unsigned cz0 = (unsigned)floorf(Z*scl);
      unsigned r1 = (unsigned)(res + 1);
      bool hl = (cfg.hashed_mask >> lev) & 1;
      unsigned base = (unsigned)cfg.off[lev];
      #pragma unroll
      for (int c = 0; c < 8; c++){
        unsigned bx = (c >> 2) & 1, by = (c >> 1) & 1, bz = c & 1;
        unsigned cx = cx0 + bx, cy = cy0 + by, cz = cz0 + bz;
        unsigned hidx = hl ? ((cx ^ (cy * 2654435761u) ^ (cz * 805459861u)) & TMASK)
                           : (cx + cy * r1 + cz * r1 * r1);
        if constexpr (USEBF) vb[ii][c] = tbf[base + hidx];
        else                 vf[ii][c] = *(const float2*)(table + (size_t)(base + hidx) * 2u);
      }
    }
  };

  // consume: recompute trilinear fractions from coords (saves registers),
  // combine gathered corners, write features + trig/input/pad rows.
  auto consume = [&](float X, float Y, float Z, unsigned (&vb)[4][8], float2 (&vf)[4][8]){
    #pragma unroll
    for (int ii = 0; ii < 4; ii++){
      int lev = grp*4 + ii;
      int res = cfg.res[lev];
      float scl = (float)(res - 1);
      float px = X*scl, py = Y*scl, pz = Z*scl;
      float wx = px - floorf(px), wy = py - floorf(py), wz = pz - floorf(pz);
      float f0 = 0.f, f1 = 0.f;
      #pragma unroll
      for (int c = 0; c < 8; c++){
        unsigned bx = (c >> 2) & 1, by = (c >> 1) & 1, bz = c & 1;
        float w = (bx ? wx : 1.f - wx) * (by ? wy : 1.f - wy) * (bz ? wz : 1.f - wz);
        if constexpr (USEBF){
          unsigned u = vb[ii][c];
          f0 += w * __uint_as_float(u << 16);
          f1 += w * __uint_as_float(u & 0xffff0000u);
        } else {
          f0 += w * vf[ii][c].x;
          f1 += w * vf[ii][c].y;
        }
      }
      stB(p, 39 + 2*lev, f0);
      stB(p, 40 + 2*lev, f1);
    }
    if (grp < 3){
      float xv[3] = {X, Y, Z};
      #pragma unroll
      for (int fi = 0; fi < 2; fi++){
        int f = grp*2 + fi;
        float fr = (float)(1 << f);
        #pragma unroll
        for (int d = 0; d < 3; d++){
          float ang = xv[d] * fr;
          stB(p, 3 + f*6 + d,     __sinf(ang));
          stB(p, 3 + f*6 + 3 + d, __cosf(ang));
        }
      }
    } else {
      stB(p, 0, X); stB(p, 1, Y); stB(p, 2, Z);
      #pragma unroll
      for (int c = 71; c < 96; c++)
        buf[p*256 + (c ^ ((p & 7) << 3))] = 0;
    }
  };

  // hidden layer: MFMA over nkt K-tiles, then activation back into buf
  auto hidden_layer = [&](const short8* Bp, int nkt, const float* bias){
    f32x4 acc[4][4];
    #pragma unroll
    for (int a = 0; a < 4; a++)
      #pragma unroll
      for (int b = 0; b < 4; b++) acc[a][b] = (f32x4){0.f,0.f,0.f,0.f};
    __builtin_amdgcn_s_setprio(1);
    for (int kt = 0; kt < nkt; kt++){
      short8 af[4];
      #pragma unroll
      for (int mt = 0; mt < 4; mt++) af[mt] = ldB(mt*16 + lr, kt*32 + lh*8);
      #pragma unroll
      for (int nt = 0; nt < 4; nt++){
        short8 bf = Bp[((wv*4 + nt)*nkt + kt)*64 + l];
        #pragma unroll
        for (int mt = 0; mt < 4; mt++)
          acc[mt][nt] = __builtin_amdgcn_mfma_f32_16x16x32_bf16(af[mt], bf, acc[mt][nt], 0, 0, 0);
      }
    }
    __builtin_amdgcn_s_setprio(0);
    __syncthreads();   // all buf reads complete before overwrite
    float bb[4];
    #pragma unroll
    for (int nt = 0; nt < 4; nt++) bb[nt] = bias[wv*64 + nt*16 + lr];
    #pragma unroll
    for (int mt = 0; mt < 4; mt++)
      #pragma unroll
      for (int nt = 0; nt < 4; nt++){
        int c = wv*64 + nt*16 + lr;
        #pragma unroll
        for (int j = 0; j < 4; j++)
          stB(mt*16 + lh*4 + j, c, softplus100_fast(acc[mt][nt][j] + bb[nt]));
      }
  };

  // output layer + stores for tile t (t is compile-time at call sites)
  auto out_layer = [&](int t){
    // last-col partials (reads h2 from buf)
    {
      float s = 0.f;
      #pragma unroll
      for (int q = 0; q < 8; q++){
        short8 h = ldB(l, wv*64 + q*8);
        #pragma unroll
        for (int j = 0; j < 8; j++)
          s += bf2f((unsigned short)h[j]) * w2l[wv*64 + q*8 + j];
      }
      colsc[wv][l] = s;
    }
    f32x4 acc[4][4];
    #pragma unroll
    for (int a = 0; a < 4; a++)
      #pragma unroll
      for (int b = 0; b < 4; b++) acc[a][b] = (f32x4){0.f,0.f,0.f,0.f};
    __builtin_amdgcn_s_setprio(1);
    for (int kt = 0; kt < 8; kt++){
      short8 af[4];
      #pragma unroll
      for (int mt = 0; mt < 4; mt++) af[mt] = ldB(mt*16 + lr, kt*32 + lh*8);
      #pragma unroll
      for (int nt = 0; nt < 4; nt++){
        short8 bf = B2p[((wv*4 + nt)*8 + kt)*64 + l];
        #pragma unroll
        for (int mt = 0; mt < 4; mt++)
          acc[mt][nt] = __builtin_amdgcn_mfma_f32_16x16x32_bf16(af[mt], bf, acc[mt][nt], 0, 0, 0);
      }
    }
    __builtin_amdgcn_s_setprio(0);
    __syncthreads();   // buf reads done (feat overwrite may follow); colsc visible
    float bb[4];
    #pragma unroll
    for (int nt = 0; nt < 4; nt++) bb[nt] = b2[wv*64 + nt*16 + lr];
    #pragma unroll
    for (int mt = 0; mt < 4; mt++)
      #pragma unroll
      for (int nt = 0; nt < 4; nt++){
        int c = wv*64 + nt*16 + lr;
        #pragma unroll
        for (int j = 0; j < 4; j++)
          out[(size_t)pids_sh[t][mt*16 + lh*4 + j]*257 + c] = acc[mt][nt][j] + bb[nt];
      }
    if (tid < 64)
      out[(size_t)pids_sh[t][tid]*257 + 256] =
        colsc[0][tid] + colsc[1][tid] + colsc[2][tid] + colsc[3][tid] + b2[256];
  };

  // ---------------- schedule ----------------
  issue(a0, a1, a2, vb0, vf0);     // tile0 gathers in flight
  issue(c0, c1, c2, vb1, vf1);     // tile1 gathers in flight (stay out through tile0 MLP)

  consume(a0, a1, a2, vb0, vf0);   // waits only on vb0
  __syncthreads();

  hidden_layer(B0p, 3, b0);
  __syncthreads();
  hidden_layer(B1p, 8, b1);
  __syncthreads();
  out_layer(0);                     // ends with syncthreads before stores

  consume(c0, c1, c2, vb1, vf1);   // vb1 long since landed; overwrites feat region
  __syncthreads();

  hidden_layer(B0p, 3, b0);
  __syncthreads();
  hidden_layer(B1p, 8, b1);
  __syncthreads();
  out_layer(1);
}

// ---- host: replicate reference's double-precision level config exactly ----
static HashCfg make_cfg(){
  HashCfg c;
  double pls = exp2(log2(2048.0 / 16.0) / 15.0);
  long long off = 0;
  unsigned mask = 0;
  for (int l = 0; l < 16; l++){
    int r = (int)ceil(16.0 * pow(pls, (double)l));
    c.res[l] = r;
    c.off[l] = (int)off;
    double n3 = (double)(r + 1) * (double)(r + 1) * (double)(r + 1);
    long long size;
    if (n3 > 524288.0){ mask |= (1u << l); }
    size = (long long)(ceil(n3 / 8.0) * 8.0);
    if (size > 524288) size = 524288;
    off += size;
  }
  c.hashed_mask = mask;
  c.total = (int)off;
  return c;
}

extern "C" void kernel_launch(void* const* d_in, const int* in_sizes, int n_in,
                              void* d_out, int out_size, void* d_ws, size_t ws_size,
                              hipStream_t stream) {
  const float* x     = (const float*)d_in[0];
  const float* table = (const float*)d_in[1];
  const float* v0 = (const float*)d_in[2];
  const float* g0 = (const float*)d_in[3];
  const float* b0 = (const float*)d_in[4];
  const float* v1 = (const float*)d_in[5];
  const float* g1 = (const float*)d_in[6];
  const float* b1 = (const float*)d_in[7];
  const float* v2 = (const float*)d_in[8];
  const float* g2 = (const float*)d_in[9];
  const float* b2 = (const float*)d_in[10];
  float* out = (float*)d_out;
  char* ws = (char*)d_ws;

  HashCfg cfg = make_cfg();
  size_t tbf_bytes = (size_t)cfg.total * 4u;
  size_t hist_off  = (TBF_OFF + tbf_bytes + 255) & ~(size_t)255;
  size_t keys_off  = hist_off + (size_t)NCELLS * 4;
  size_t perm_off  = keys_off + (size_t)N_POINTS * 4;
  size_t sx_off    = perm_off + (size_t)N_POINTS * 4;
  size_t need_sort = sx_off + (size_t)N_POINTS * 12;
  size_t need_bf   = TBF_OFF + tbf_bytes;

  hipLaunchKernelGGL(scale_kernel, dim3(4), dim3(256), 0, stream, v0, g0, v1, g1, v2, g2, ws);
  hipLaunchKernelGGL(pack_kernel, dim3(609), dim3(256), 0, stream, v0, v1, v2, ws);

  const int nblk = N_POINTS / 128;   // 4096

  if (ws_size >= need_sort){
    unsigned* hist = (unsigned*)(ws + hist_off);
    unsigned* keys = (unsigned*)(ws + keys_off);
    int*      perm = (int*)(ws + perm_off);
    float*    sx   = (float*)(ws + sx_off);
    hipMemsetAsync(hist, 0, (size_t)NCELLS * 4, stream);
    hipLaunchKernelGGL(tconv_kernel, dim3((cfg.total + 255) / 256), dim3(256), 0, stream,
                       table, ws, cfg.total);
    hipLaunchKernelGGL(hist_kernel, dim3(N_POINTS / 256), dim3(256), 0, stream, x, hist, keys);
    hipLaunchKernelGGL(scan_kernel, dim3(1), dim3(1024), 0, stream, hist);
    hipLaunchKernelGGL(scatter_kernel, dim3(N_POINTS / 256), dim3(256), 0, stream,
                       x, keys, hist, perm, sx);
    hipLaunchKernelGGL((fused6<1>), dim3(nblk), dim3(256), 0, stream,
                       x, table, ws, perm, sx, b0, b1, b2, out, cfg);
  } else if (ws_size >= need_bf){
    hipLaunchKernelGGL(tconv_kernel, dim3((cfg.total + 255) / 256), dim3(256), 0, stream,
                       table, ws, cfg.total);
    hipLaunchKernelGGL((fused6<1>), dim3(nblk), dim3(256), 0, stream,
                       x, table, ws, (const int*)nullptr, (const float*)nullptr,
                       b0, b1, b2, out, cfg);
  } else {
    hipLaunchKernelGGL((fused6<0>), dim3(nblk), dim3(256), 0, stream,
                       x, table, ws, (const int*)nullptr, (const float*)nullptr,
                       b0, b1, b2, out, cfg);
  }
}

// Round 9
// 788.208 us; speedup vs baseline: 1.3665x; 1.3665x over previous
//
#include <hip/hip_runtime.h>
#include <cmath>

typedef float f32x4 __attribute__((ext_vector_type(4)));
typedef short short8 __attribute__((ext_vector_type(8)));

#define N_POINTS 524288
#define TMASK 0x7FFFFu   // T_MAX-1, hashed levels all have size 2^19
#define NCELLS 32768     // 32^3 Morton cells

struct HashCfg { int res[16]; int off[16]; unsigned hashed_mask; int total; };

// ---- ws layout (bytes) ----
#define S0_OFF   0
#define S1_OFF   1024
#define S2_OFF   2048
#define W2L_OFF  3328
#define B0_OFF   4608
#define B1_OFF   (B0_OFF + 49152)
#define B2_OFF   (B1_OFF + 131072)
#define TBF_OFF  (B2_OFF + 131072)   // bf16x2 table copy (~24.5 MB); sort arrays after

__device__ inline unsigned short f2bf(float f){
  unsigned u = __float_as_uint(f);
  u = (u + 0x7FFFu + ((u >> 16) & 1u)) >> 16;
  return (unsigned short)u;
}
__device__ inline float bf2f(unsigned short h){
  return __uint_as_float(((unsigned)h) << 16);
}
__device__ inline float softplus100_fast(float x){
  float y = 100.f * x;
  return 0.01f * (fmaxf(y, 0.f) + __logf(1.f + __expf(-fabsf(y))));
}
__device__ inline unsigned morton5(unsigned cx, unsigned cy, unsigned cz){
  unsigned k = 0;
  #pragma unroll
  for (int b = 0; b < 5; b++){
    k |= ((cx >> b) & 1u) << (3*b)
       | ((cy >> b) & 1u) << (3*b + 1)
       | ((cz >> b) & 1u) << (3*b + 2);
  }
  return k;
}

// ---- precompute 1: weight-norm row scales ----
__global__ void scale_kernel(const float* __restrict__ v0, const float* __restrict__ g0,
                             const float* __restrict__ v1, const float* __restrict__ g1,
                             const float* __restrict__ v2, const float* __restrict__ g2,
                             char* __restrict__ ws){
  int r = blockIdx.x * 256 + threadIdx.x;
  if (r < 256){
    float s = 0.f;
    for (int k = 0; k < 71; k++){ float t = v0[r*71+k]; s += t*t; }
    ((float*)(ws + S0_OFF))[r] = g0[r] / sqrtf(s);
  } else if (r < 512){
    int o = r - 256; float s = 0.f;
    for (int k = 0; k < 256; k++){ float t = v1[o*256+k]; s += t*t; }
    ((float*)(ws + S1_OFF))[o] = g1[o] / sqrtf(s);
  } else if (r < 769){
    int o = r - 512; float s = 0.f;
    for (int k = 0; k < 256; k++){ float t = v2[o*256+k]; s += t*t; }
    ((float*)(ws + S2_OFF))[o] = g2[o] / sqrtf(s);
  }
}

// ---- precompute 2: pack normalized weights into MFMA B-fragment order (bf16) ----
__global__ void pack_kernel(const float* __restrict__ v0, const float* __restrict__ v1,
                            const float* __restrict__ v2, char* __restrict__ ws){
  int i = blockIdx.x * 256 + threadIdx.x;
  const float* s0 = (const float*)(ws + S0_OFF);
  const float* s1 = (const float*)(ws + S1_OFF);
  const float* s2 = (const float*)(ws + S2_OFF);
  if (i < 24576){
    int j = i & 7, l = (i >> 3) & 63, q = i >> 9;
    int kt = q % 3, nt = q / 3;
    int k = kt*32 + (l >> 4)*8 + j, col = nt*16 + (l & 15);
    float v = (k < 71) ? v0[col*71 + k] * s0[col] : 0.f;
    ((unsigned short*)(ws + B0_OFF))[i] = f2bf(v);
  } else if (i < 90112){
    int e = i - 24576;
    int j = e & 7, l = (e >> 3) & 63, q = e >> 9;
    int kt = q & 7, nt = q >> 3;
    int k = kt*32 + (l >> 4)*8 + j, col = nt*16 + (l & 15);
    ((unsigned short*)(ws + B1_OFF))[e] = f2bf(v1[col*256 + k] * s1[col]);
  } else if (i < 155648){
    int e = i - 90112;
    int j = e & 7, l = (e >> 3) & 63, q = e >> 9;
    int kt = q & 7, nt = q >> 3;
    int k = kt*32 + (l >> 4)*8 + j, col = nt*16 + (l & 15);
    ((unsigned short*)(ws + B2_OFF))[e] = f2bf(v2[col*256 + k] * s2[col]);
  } else if (i < 155904){
    int k = i - 155648;
    ((float*)(ws + W2L_OFF))[k] = v2[256*256 + k] * s2[256];
  }
}

// ---- precompute 3: table f32 -> packed bf16x2 ----
__global__ void tconv_kernel(const float* __restrict__ table, char* __restrict__ ws, int total){
  int i = blockIdx.x * 256 + threadIdx.x;
  if (i < total){
    float2 v = ((const float2*)table)[i];
    ((unsigned*)(ws + TBF_OFF))[i] = ((unsigned)f2bf(v.x)) | (((unsigned)f2bf(v.y)) << 16);
  }
}

// ---- sort passes ----
__global__ void hist_kernel(const float* __restrict__ xin,
                            unsigned* __restrict__ hist, unsigned* __restrict__ keys){
  int i = blockIdx.x * 256 + threadIdx.x;
  float x0 = xin[i*3], x1 = xin[i*3+1], x2 = xin[i*3+2];
  unsigned cx = min(31u, (unsigned)(x0 * 32.f));
  unsigned cy = min(31u, (unsigned)(x1 * 32.f));
  unsigned cz = min(31u, (unsigned)(x2 * 32.f));
  unsigned k = morton5(cx, cy, cz);
  keys[i] = k;
  atomicAdd(&hist[k], 1u);
}

__global__ __launch_bounds__(1024) void scan_kernel(unsigned* __restrict__ hist){
  __shared__ unsigned sdata[1024];
  int t = threadIdx.x;
  unsigned loc[32];
  unsigned s = 0;
  #pragma unroll
  for (int k = 0; k < 32; k++){ loc[k] = hist[t*32 + k]; s += loc[k]; }
  sdata[t] = s;
  __syncthreads();
  for (int d = 1; d < 1024; d <<= 1){
    unsigned v = (t >= d) ? sdata[t - d] : 0u;
    __syncthreads();
    sdata[t] += v;
    __syncthreads();
  }
  unsigned run = (t == 0) ? 0u : sdata[t - 1];
  #pragma unroll
  for (int k = 0; k < 32; k++){ unsigned c = loc[k]; hist[t*32 + k] = run; run += c; }
}

// scatter + build pre-permuted coordinate array sx[r*3..] = x[perm[r]*3..]
__global__ void scatter_kernel(const float* __restrict__ xin,
                               const unsigned* __restrict__ keys,
                               unsigned* __restrict__ hist, int* __restrict__ perm,
                               float* __restrict__ sx){
  int i = blockIdx.x * 256 + threadIdx.x;
  unsigned k = keys[i];
  unsigned r = atomicAdd(&hist[k], 1u);
  perm[r] = i;
  sx[r*3]   = xin[i*3];
  sx[r*3+1] = xin[i*3+1];
  sx[r*3+2] = xin[i*3+2];
}

// ============================================================================
// Fused v7: 512 threads, 128 sorted points per block (one M=128 tile).
// Phase-local gathers (regs dead before MFMA), 8 waves in 2M x 4N grid.
// ============================================================================
template<int USEBF>
__global__ __launch_bounds__(512, 4) void fused7(
    const float* __restrict__ xin, const float* __restrict__ table,
    char* __restrict__ ws, const int* __restrict__ perm, const float* __restrict__ sx,
    const float* __restrict__ b0, const float* __restrict__ b1, const float* __restrict__ b2,
    float* __restrict__ out, HashCfg cfg)
{
  __shared__ unsigned short buf[128 * 256];  // swizzled: elem(row,col) at col^((row&7)<<3)
  __shared__ float colsc[4][128];
  __shared__ int pids_sh[128];

  const int tid  = threadIdx.x;
  const int p    = tid & 127;        // point for gather/feature phase
  const int lgrp = tid >> 7;         // 0..3: level-group / trig role
  const int grp  = tid >> 6;         // wave id 0..7
  const int wm   = grp >> 2;         // row-tile (0..1): rows wm*64..+64
  const int wn   = grp & 3;          // col-tile (0..3): cols wn*64..+64
  const int l    = tid & 63;
  const int lr   = l & 15;
  const int lh   = l >> 4;
  // bijective XCD swizzle over 4096 blocks (8 * 512)
  const int lb   = (blockIdx.x & 7) * 512 + (blockIdx.x >> 3);
  const int base_idx = lb * 128;

  const unsigned* __restrict__ tbf = (const unsigned*)(ws + TBF_OFF);
  const short8* B0p = (const short8*)(ws + B0_OFF);
  const short8* B1p = (const short8*)(ws + B1_OFF);
  const short8* B2p = (const short8*)(ws + B2_OFF);
  const float* w2l = (const float*)(ws + W2L_OFF);

  auto stB = [&](int row, int col, float v){
    buf[row*256 + (col ^ ((row & 7) << 3))] = f2bf(v);
  };
  auto ldB = [&](int row, int kb) -> short8 {
    return *(const short8*)&buf[row*256 + (kb ^ ((row & 7) << 3))];
  };

  if (tid < 128) pids_sh[tid] = perm ? perm[base_idx + tid] : (base_idx + tid);

  // ---------- phase E: gather (4 levels/thread) + trig, phase-local regs ----------
  {
    const float* src = sx ? sx : xin;
    const float X = src[(base_idx + p)*3];
    const float Y = src[(base_idx + p)*3 + 1];
    const float Z = src[(base_idx + p)*3 + 2];

    unsigned vb[4][8];
    float2   vf2[4][8];   // f32-table fallback only (dead when USEBF=1)

    #pragma unroll
    for (int ii = 0; ii < 4; ii++){
      int lev = lgrp*4 + ii;
      int res = cfg.res[lev];
      float scl = (float)(res - 1);
      unsigned cx0 = (unsigned)floorf(X*scl);
      unsigned cy0 = (unsigned)floorf(Y*scl);
      unsigned cz0 = (unsigned)floorf(Z*scl);
      unsigned r1 = (unsigned)(res + 1);
      bool hl = (cfg.hashed_mask >> lev) & 1;
      unsigned base = (unsigned)cfg.off[lev];
      #pragma unroll
      for (int c = 0; c < 8; c++){
        unsigned bx = (c >> 2) & 1, by = (c >> 1) & 1, bz = c & 1;
        unsigned cx = cx0 + bx, cy = cy0 + by, cz = cz0 + bz;
        unsigned hidx = hl ? ((cx ^ (cy * 2654435761u) ^ (cz * 805459861u)) & TMASK)
                           : (cx + cy * r1 + cz * r1 * r1);
        if constexpr (USEBF) vb[ii][c]  = tbf[base + hidx];
        else                 vf2[ii][c] = *(const float2*)(table + (size_t)(base + hidx) * 2u);
      }
    }

    // trig / input / K-pad overlaps gather latency
    if (lgrp < 3){
      float xv[3] = {X, Y, Z};
      #pragma unroll
      for (int fi = 0; fi < 2; fi++){
        int f = lgrp*2 + fi;
        float fr = (float)(1 << f);
        #pragma unroll
        for (int d = 0; d < 3; d++){
          float ang = xv[d] * fr;
          stB(p, 3 + f*6 + d,     __sinf(ang));
          stB(p, 3 + f*6 + 3 + d, __cosf(ang));
        }
      }
    } else {
      stB(p, 0, X); stB(p, 1, Y); stB(p, 2, Z);
      #pragma unroll
      for (int c = 71; c < 96; c++)
        buf[p*256 + (c ^ ((p & 7) << 3))] = 0;
    }

    // consume
    #pragma unroll
    for (int ii = 0; ii < 4; ii++){
      int lev = lgrp*4 + ii;
      int res = cfg.res[lev];
      float scl = (float)(res - 1);
      float px = X*scl, py = Y*scl, pz = Z*scl;
      float wx = px - floorf(px), wy = py - floorf(py), wz = pz - floorf(pz);
      float f0 = 0.f, f1 = 0.f;
      #pragma unroll
      for (int c = 0; c < 8; c++){
        unsigned bx = (c >> 2) & 1, by = (c >> 1) & 1, bz = c & 1;
        float w = (bx ? wx : 1.f - wx) * (by ? wy : 1.f - wy) * (bz ? wz : 1.f - wz);
        if constexpr (USEBF){
          unsigned u = vb[ii][c];
          f0 += w * __uint_as_float(u << 16);
          f1 += w * __uint_as_float(u & 0xffff0000u);
        } else {
          f0 += w * vf2[ii][c].x;
          f1 += w * vf2[ii][c].y;
        }
      }
      stB(p, 39 + 2*lev, f0);
      stB(p, 40 + 2*lev, f1);
    }
  }
  __syncthreads();

  // ---------- MFMA layers ----------
  auto hidden_layer = [&](const short8* Bp, int nkt, const float* bias){
    f32x4 acc[4][4];
    #pragma unroll
    for (int a = 0; a < 4; a++)
      #pragma unroll
      for (int b = 0; b < 4; b++) acc[a][b] = (f32x4){0.f,0.f,0.f,0.f};
    __builtin_amdgcn_s_setprio(1);
    for (int kt = 0; kt < nkt; kt++){
      short8 af[4];
      #pragma unroll
      for (int mt = 0; mt < 4; mt++) af[mt] = ldB(wm*64 + mt*16 + lr, kt*32 + lh*8);
      #pragma unroll
      for (int nt = 0; nt < 4; nt++){
        short8 bf = Bp[((wn*4 + nt)*nkt + kt)*64 + l];
        #pragma unroll
        for (int mt = 0; mt < 4; mt++)
          acc[mt][nt] = __builtin_amdgcn_mfma_f32_16x16x32_bf16(af[mt], bf, acc[mt][nt], 0, 0, 0);
      }
    }
    __builtin_amdgcn_s_setprio(0);
    __syncthreads();   // all buf reads complete before overwrite
    float bb[4];
    #pragma unroll
    for (int nt = 0; nt < 4; nt++) bb[nt] = bias[wn*64 + nt*16 + lr];
    #pragma unroll
    for (int mt = 0; mt < 4; mt++)
      #pragma unroll
      for (int nt = 0; nt < 4; nt++){
        int c = wn*64 + nt*16 + lr;
        #pragma unroll
        for (int j = 0; j < 4; j++)
          stB(wm*64 + mt*16 + lh*4 + j, c, softplus100_fast(acc[mt][nt][j] + bb[nt]));
      }
  };

  hidden_layer(B0p, 3, b0);
  __syncthreads();
  hidden_layer(B1p, 8, b1);
  __syncthreads();

  // last-col partials: thread handles row (tid&127), col chunk (tid>>7)*64..+64
  {
    int row = tid & 127, ch = tid >> 7;
    float s = 0.f;
    #pragma unroll
    for (int q = 0; q < 8; q++){
      short8 h = ldB(row, ch*64 + q*8);
      #pragma unroll
      for (int j = 0; j < 8; j++)
        s += bf2f((unsigned short)h[j]) * w2l[ch*64 + q*8 + j];
    }
    colsc[ch][row] = s;
  }

  { // ----- layer 2 + scattered stores -----
    f32x4 acc[4][4];
    #pragma unroll
    for (int a = 0; a < 4; a++)
      #pragma unroll
      for (int b = 0; b < 4; b++) acc[a][b] = (f32x4){0.f,0.f,0.f,0.f};
    __builtin_amdgcn_s_setprio(1);
    for (int kt = 0; kt < 8; kt++){
      short8 af[4];
      #pragma unroll
      for (int mt = 0; mt < 4; mt++) af[mt] = ldB(wm*64 + mt*16 + lr, kt*32 + lh*8);
      #pragma unroll
      for (int nt = 0; nt < 4; nt++){
        short8 bf = B2p[((wn*4 + nt)*8 + kt)*64 + l];
        #pragma unroll
        for (int mt = 0; mt < 4; mt++)
          acc[mt][nt] = __builtin_amdgcn_mfma_f32_16x16x32_bf16(af[mt], bf, acc[mt][nt], 0, 0, 0);
      }
    }
    __builtin_amdgcn_s_setprio(0);
    __syncthreads();   // colsc partials visible
    float bb[4];
    #pragma unroll
    for (int nt = 0; nt < 4; nt++) bb[nt] = b2[wn*64 + nt*16 + lr];
    #pragma unroll
    for (int mt = 0; mt < 4; mt++)
      #pragma unroll
      for (int nt = 0; nt < 4; nt++){
        int c = wn*64 + nt*16 + lr;
        #pragma unroll
        for (int j = 0; j < 4; j++)
          out[(size_t)pids_sh[wm*64 + mt*16 + lh*4 + j]*257 + c] = acc[mt][nt][j] + bb[nt];
      }
    if (tid < 128)
      out[(size_t)pids_sh[tid]*257 + 256] =
        colsc[0][tid] + colsc[1][tid] + colsc[2][tid] + colsc[3][tid] + b2[256];
  }
}

// ---- host: replicate reference's double-precision level config exactly ----
static HashCfg make_cfg(){
  HashCfg c;
  double pls = exp2(log2(2048.0 / 16.0) / 15.0);
  long long off = 0;
  unsigned mask = 0;
  for (int l = 0; l < 16; l++){
    int r = (int)ceil(16.0 * pow(pls, (double)l));
    c.res[l] = r;
    c.off[l] = (int)off;
    double n3 = (double)(r + 1) * (double)(r + 1) * (double)(r + 1);
    long long size;
    if (n3 > 524288.0){ mask |= (1u << l); }
    size = (long long)(ceil(n3 / 8.0) * 8.0);
    if (size > 524288) size = 524288;
    off += size;
  }
  c.hashed_mask = mask;
  c.total = (int)off;
  return c;
}

extern "C" void kernel_launch(void* const* d_in, const int* in_sizes, int n_in,
                              void* d_out, int out_size, void* d_ws, size_t ws_size,
                              hipStream_t stream) {
  const float* x     = (const float*)d_in[0];
  const float* table = (const float*)d_in[1];
  const float* v0 = (const float*)d_in[2];
  const float* g0 = (const float*)d_in[3];
  const float* b0 = (const float*)d_in[4];
  const float* v1 = (const float*)d_in[5];
  const float* g1 = (const float*)d_in[6];
  const float* b1 = (const float*)d_in[7];
  const float* v2 = (const float*)d_in[8];
  const float* g2 = (const float*)d_in[9];
  const float* b2 = (const float*)d_in[10];
  float* out = (float*)d_out;
  char* ws = (char*)d_ws;

  HashCfg cfg = make_cfg();
  size_t tbf_bytes = (size_t)cfg.total * 4u;
  size_t hist_off  = (TBF_OFF + tbf_bytes + 255) & ~(size_t)255;
  size_t keys_off  = hist_off + (size_t)NCELLS * 4;
  size_t perm_off  = keys_off + (size_t)N_POINTS * 4;
  size_t sx_off    = perm_off + (size_t)N_POINTS * 4;
  size_t need_sort = sx_off + (size_t)N_POINTS * 12;
  size_t need_bf   = TBF_OFF + tbf_bytes;

  hipLaunchKernelGGL(scale_kernel, dim3(4), dim3(256), 0, stream, v0, g0, v1, g1, v2, g2, ws);
  hipLaunchKernelGGL(pack_kernel, dim3(609), dim3(256), 0, stream, v0, v1, v2, ws);

  const int nblk = N_POINTS / 128;   // 4096

  if (ws_size >= need_sort){
    unsigned* hist = (unsigned*)(ws + hist_off);
    unsigned* keys = (unsigned*)(ws + keys_off);
    int*      perm = (int*)(ws + perm_off);
    float*    sx   = (float*)(ws + sx_off);
    hipMemsetAsync(hist, 0, (size_t)NCELLS * 4, stream);
    hipLaunchKernelGGL(tconv_kernel, dim3((cfg.total + 255) / 256), dim3(256), 0, stream,
                       table, ws, cfg.total);
    hipLaunchKernelGGL(hist_kernel, dim3(N_POINTS / 256), dim3(256), 0, stream, x, hist, keys);
    hipLaunchKernelGGL(scan_kernel, dim3(1), dim3(1024), 0, stream, hist);
    hipLaunchKernelGGL(scatter_kernel, dim3(N_POINTS / 256), dim3(256), 0, stream,
                       x, keys, hist, perm, sx);
    hipLaunchKernelGGL((fused7<1>), dim3(nblk), dim3(512), 0, stream,
                       x, table, ws, perm, sx, b0, b1, b2, out, cfg);
  } else if (ws_size >= need_bf){
    hipLaunchKernelGGL(tconv_kernel, dim3((cfg.total + 255) / 256), dim3(256), 0, stream,
                       table, ws, cfg.total);
    hipLaunchKernelGGL((fused7<1>), dim3(nblk), dim3(512), 0, stream,
                       x, table, ws, (const int*)nullptr, (const float*)nullptr,
                       b0, b1, b2, out, cfg);
  } else {
    hipLaunchKernelGGL((fused7<0>), dim3(nblk), dim3(512), 0, stream,
                       x, table, ws, (const int*)nullptr, (const float*)nullptr,
                       b0, b1, b2, out, cfg);
  }
}